// Round 14
// baseline (678.185 us; speedup 1.0000x reference)
//
#include <hip/hip_runtime.h>
#include <hip/hip_cooperative_groups.h>
#include <math.h>

namespace cgx = cooperative_groups;

#define EPSN 1e-4f
#define SEQ 2304

using bf16x8 = __attribute__((ext_vector_type(8))) short;
using f32x4  = __attribute__((ext_vector_type(4))) float;

// HW packed f32->bf16 (RNE), gfx950.
__device__ inline unsigned cvt_pk_bf16(float lo, float hi) {
    unsigned r;
    asm("v_cvt_pk_bf16_f32 %0, %1, %2" : "=v"(r) : "v"(lo), "v"(hi));
    return r;
}
// gfx950 cross-row swaps (verified passing R3-R12).
__device__ inline void permlane32_swap(unsigned &a, unsigned &b) {
    asm("v_permlane32_swap_b32 %0, %1" : "+v"(a), "+v"(b));
}
__device__ inline void permlane16_swap(unsigned &a, unsigned &b) {
    asm("v_permlane16_swap_b32 %0, %1" : "+v"(a), "+v"(b));
}

// ================= shared stage bodies (verbatim R12/R10 256-thread kernels) ==============

// prep: weight-norm for 4 rows (one per wave). bid in [0,256).
__device__ __forceinline__ void prep_body(int bid, int tid,
                                          const float* __restrict__ w_qkv,
                                          const float* __restrict__ w_out,
                                          unsigned short* __restrict__ wqb,
                                          unsigned short* __restrict__ wob) {
    int wave = tid >> 6, lane = tid & 63;
    int row = bid * 4 + wave;
    const float* src;
    unsigned short* dst;
    if (row < 768) { src = w_qkv + (size_t)row * 256; dst = wqb + (size_t)row * 256; }
    else           { src = w_out + (size_t)(row - 768) * 256; dst = wob + (size_t)(row - 768) * 256; }
    float4 v = *(const float4*)&src[lane * 4];
    float ss = v.x * v.x + v.y * v.y + v.z * v.z + v.w * v.w;
    for (int off = 32; off > 0; off >>= 1) ss += __shfl_xor(ss, off, 64);
    float sc = 1.0f / (sqrtf(ss) + 16.0f * EPSN);
    *(uint2*)&dst[lane * 4] = make_uint2(cvt_pk_bf16(v.x * sc, v.y * sc),
                                        cvt_pk_bf16(v.z * sc, v.w * sc));
}

// qkv: R12 body. bid in [0,1152). SMEM >= 33792 B.
__device__ __forceinline__ void qkv_body(int bid, int tid, unsigned char* SMEM,
                                         const float* __restrict__ x,
                                         const unsigned short* __restrict__ wqb,
                                         unsigned short* __restrict__ qn,
                                         unsigned short* __restrict__ kn,
                                         unsigned short* __restrict__ vn) {
    unsigned short (*Xs)[264] = (unsigned short (*)[264])SMEM;            // 16896 B
    float (*Cs)[33] = (float (*)[33])(SMEM + 16896);                      // 12672 B
    float (*Vf)[33] = (float (*)[33])(SMEM + 29568);                      // 4224 B
    int xcd = bid & 7, j = bid >> 3;
    int h = j & 7;
    int tile = xcd * 18 + (j >> 3);
    int st2 = tile % 72, n = tile / 72;
    int wave = tid >> 6, lane = tid & 63;
    int ln = lane & 15, quad = lane >> 4;
    int sgrp = wave & 1, mgrp = wave >> 1;
    int s0 = st2 * 32;
    {
        int cpair = tid >> 3, sq = tid & 7;
#pragma unroll
        for (int p = 0; p < 4; ++p) {
            int c = (p * 32 + cpair) * 2;
            const float* xb = &x[(size_t)(n * 256 + c) * SEQ + s0 + sq * 4];
            float4 a = *(const float4*)xb;
            float4 b = *(const float4*)(xb + SEQ);
            *(unsigned*)&Xs[sq * 4 + 0][c] = cvt_pk_bf16(a.x, b.x);
            *(unsigned*)&Xs[sq * 4 + 1][c] = cvt_pk_bf16(a.y, b.y);
            *(unsigned*)&Xs[sq * 4 + 2][c] = cvt_pk_bf16(a.z, b.z);
            *(unsigned*)&Xs[sq * 4 + 3][c] = cvt_pk_bf16(a.w, b.w);
        }
    }
    __syncthreads();
    const unsigned short* Abase = wqb + (size_t)(h * 96 + mgrp * 48 + ln) * 256 + quad * 8;
    f32x4 acc[3];
#pragma unroll
    for (int m = 0; m < 3; ++m) acc[m] = (f32x4){0.f, 0.f, 0.f, 0.f};
#pragma unroll
    for (int kc = 0; kc < 8; ++kc) {
        bf16x8 b = *(const bf16x8*)&Xs[sgrp * 16 + ln][kc * 32 + quad * 8];
#pragma unroll
        for (int m = 0; m < 3; ++m) {
            bf16x8 a = *(const bf16x8*)(Abase + (size_t)(m * 16) * 256 + kc * 32);
            acc[m] = __builtin_amdgcn_mfma_f32_16x16x32_bf16(a, b, acc[m], 0, 0, 0);
        }
    }
#pragma unroll
    for (int m = 0; m < 3; ++m)
#pragma unroll
        for (int r = 0; r < 4; ++r)
            Cs[mgrp * 48 + m * 16 + quad * 4 + r][sgrp * 16 + ln] = acc[m][r];
    __syncthreads();
    int nh = n * 8 + h;
    if (tid < 96) {
        int sl = tid & 31, wh = tid >> 5;
        int s = st2 * 32 + sl;
        float v[32];
        float ss = 0.f;
#pragma unroll
        for (int d = 0; d < 32; ++d) { v[d] = Cs[3 * d + wh][sl]; ss += v[d] * v[d]; }
        float inv = 1.0f / (EPSN + sqrtf(ss * (1.0f / 32.0f)));
        // fold softmax scale (1/sqrt(32)) AND log2(e) into q so attn uses exp2
        if (wh == 0) inv *= 0.17677669529663687f * 1.4426950408889634f;
        if (wh == 2) {
#pragma unroll
            for (int d = 0; d < 32; ++d) Vf[d][sl] = v[d] * inv;
        } else {
            unsigned short* dst = (wh == 1 ? kn : qn) + (size_t)nh * 73728 + (size_t)s * 32;
            unsigned wbuf[16];
#pragma unroll
            for (int j2 = 0; j2 < 16; ++j2)
                wbuf[j2] = cvt_pk_bf16(v[2 * j2] * inv, v[2 * j2 + 1] * inv);
#pragma unroll
            for (int j2 = 0; j2 < 4; ++j2) {
                uint4 t4 = make_uint4(wbuf[4 * j2], wbuf[4 * j2 + 1], wbuf[4 * j2 + 2], wbuf[4 * j2 + 3]);
                *(uint4*)(dst + j2 * 8) = t4;
            }
        }
    }
    __syncthreads();
    {
        int d = tid >> 3, sj = (tid & 7) * 4;
        float r0 = Vf[d][sj + 0], r1 = Vf[d][sj + 1];
        float r2 = Vf[d][sj + 2], r3 = Vf[d][sj + 3];
        *(uint2*)&vn[(size_t)nh * 73728 + (size_t)d * SEQ + st2 * 32 + sj] =
            make_uint2(cvt_pk_bf16(r0, r1), cvt_pk_bf16(r2, r3));
    }
}

// attn: R10 body (256 thr, fragment-major LDS, split-K=4). bid in [0,2304). SMEM >= 16384 B.
__device__ __forceinline__ void attn_body(int bid, int tid, unsigned char* SMEM,
                                          const unsigned short* __restrict__ qn,
                                          const unsigned short* __restrict__ kn,
                                          const unsigned short* __restrict__ vn,
                                          float* __restrict__ Opart,
                                          float* __restrict__ Lpart) {
    unsigned char (*Ksm)[4096] = (unsigned char (*)[4096])SMEM;
    unsigned char (*Vsm)[4096] = (unsigned char (*)[4096])(SMEM + 8192);
    int wq = tid >> 6, lane = tid & 63;
    int ln = lane & 15, quad = lane >> 4;
    int xcd = bid & 7, bi = bid >> 3;       // bi 0..287
    int nh = xcd * 2 + (bi >= 144);
    int bi2 = (bi >= 144) ? bi - 144 : bi;  // 0..143
    int qt = bi2 % 36, kz = bi2 / 36;       // kz 0..3
    const unsigned short* Qg = qn + (size_t)nh * 73728;
    const unsigned short* Kg = kn + (size_t)nh * 73728;
    const unsigned short* Vg = vn + (size_t)nh * 73728;

    bf16x8 qf = *(const bf16x8*)(Qg + (size_t)(qt * 64 + wq * 16 + ln) * 32 + quad * 8);
    bf16x8 ones;
#pragma unroll
    for (int i = 0; i < 8; ++i) ones[i] = (short)0x3F80;

    f32x4 o0 = {0.f, 0.f, 0.f, 0.f};
    f32x4 o1 = {0.f, 0.f, 0.f, 0.f};
    f32x4 lac = {0.f, 0.f, 0.f, 0.f};

    const int NT = 9;
    int s0 = kz * NT * 64;

    int kr = tid >> 2, kg = tid & 3;
    int koff = ((kr >> 4) << 10) | (((kg << 4) | (kr & 15)) << 4);
    int vd = tid >> 3, vg = tid & 7;
    int voff = (((vg >> 2) * 2 + (vd >> 4)) << 10) | ((((vg & 3) << 4) | (vd & 15)) << 4);
    int lb = lane << 4;

    auto compute_tile = [&](int bsel) {
        const f32x4 zero = {0.f, 0.f, 0.f, 0.f};
        unsigned w[4][2];
#pragma unroll
        for (int c = 0; c < 4; ++c) {
            bf16x8 kf = *(const bf16x8*)(Ksm[bsel] + c * 1024 + lb);
            // swapped: lane holds S[q=ln][k=c*16+quad*4+r]
            f32x4 sc = __builtin_amdgcn_mfma_f32_16x16x32_bf16(kf, qf, zero, 0, 0, 0);
            w[c][0] = cvt_pk_bf16(exp2f(sc[0]), exp2f(sc[1]));
            w[c][1] = cvt_pk_bf16(exp2f(sc[2]), exp2f(sc[3]));
        }
#pragma unroll
        for (int kc = 0; kc < 2; ++kc) {
            unsigned a0 = w[2 * kc][0], b0 = w[2 * kc + 1][0];
            permlane32_swap(a0, b0);
            permlane16_swap(a0, b0);
            unsigned a1 = w[2 * kc][1], b1 = w[2 * kc + 1][1];
            permlane32_swap(a1, b1);
            permlane16_swap(a1, b1);
            union { unsigned u[4]; bf16x8 v8; } pk;
            pk.u[0] = a0; pk.u[1] = a1; pk.u[2] = b0; pk.u[3] = b1;
            bf16x8 v0 = *(const bf16x8*)(Vsm[bsel] + (kc * 2 + 0) * 1024 + lb);
            bf16x8 v1 = *(const bf16x8*)(Vsm[bsel] + (kc * 2 + 1) * 1024 + lb);
            lac = __builtin_amdgcn_mfma_f32_16x16x32_bf16(pk.v8, ones, lac, 0, 0, 0);
            o0  = __builtin_amdgcn_mfma_f32_16x16x32_bf16(pk.v8, v0, o0, 0, 0, 0);
            o1  = __builtin_amdgcn_mfma_f32_16x16x32_bf16(pk.v8, v1, o1, 0, 0, 0);
        }
    };

    uint4 kA = *(const uint4*)(Kg + (size_t)s0 * 32 + tid * 8);
    uint4 vA = *(const uint4*)(Vg + (size_t)(tid >> 3) * SEQ + s0 + (tid & 7) * 8);
    *(uint4*)(Ksm[0] + koff) = kA;
    *(uint4*)(Vsm[0] + voff) = vA;
    uint4 kB = *(const uint4*)(Kg + (size_t)(s0 + 64) * 32 + tid * 8);
    uint4 vB = *(const uint4*)(Vg + (size_t)(tid >> 3) * SEQ + (s0 + 64) + (tid & 7) * 8);

    for (int i = 0; i < NT; i += 2) {
        if (i + 2 < NT) {
            int sn = s0 + (i + 2) * 64;
            kA = *(const uint4*)(Kg + (size_t)sn * 32 + tid * 8);
            vA = *(const uint4*)(Vg + (size_t)(tid >> 3) * SEQ + sn + (tid & 7) * 8);
        }
        __syncthreads();
        compute_tile(0);
        if (i + 1 < NT) {
            *(uint4*)(Ksm[1] + koff) = kB;
            *(uint4*)(Vsm[1] + voff) = vB;
        }
        if (i + 3 < NT) {
            int sn = s0 + (i + 3) * 64;
            kB = *(const uint4*)(Kg + (size_t)sn * 32 + tid * 8);
            vB = *(const uint4*)(Vg + (size_t)(tid >> 3) * SEQ + sn + (tid & 7) * 8);
        }
        __syncthreads();
        if (i + 1 < NT) compute_tile(1);
        if (i + 2 < NT) {
            *(uint4*)(Ksm[0] + koff) = kA;
            *(uint4*)(Vsm[0] + voff) = vA;
        }
    }

    float* Ob = Opart + ((size_t)(kz * 16 + nh) * 36 + qt) * 2048;
    float* Lb = Lpart + ((size_t)(kz * 16 + nh) * 36 + qt) * 64;
#pragma unroll
    for (int r = 0; r < 4; ++r) {
        int ql = wq * 16 + quad * 4 + r;
        Ob[ql * 32 + ln]      = o0[r];
        Ob[ql * 32 + 16 + ln] = o1[r];
        if (ln == 0) Lb[ql] = lac[r];
    }
}

// out: R12 body (fused split-K reduce + out GEMM + residual). bid in [0,1152). SMEM >= 8960 B.
__device__ __forceinline__ void out_body(int bid, int tid, unsigned char* SMEM,
                                         const float* __restrict__ Opart,
                                         const float* __restrict__ Lpart,
                                         const unsigned short* __restrict__ wob,
                                         const float* __restrict__ x,
                                         float* __restrict__ out) {
    float (*Linv)[16] = (float (*)[16])SMEM;                              // 512 B
    unsigned short (*Ys)[264] = (unsigned short (*)[264])(SMEM + 512);    // 8448 B
    int xcd = bid & 7, j = bid >> 3;
    int mt = j & 3;
    int u = j >> 2;
    int n = u & 1;
    int st = xcd * 18 + (u >> 1);
    int qt = st >> 2;
    int qo = (st & 3) * 16;
    if (tid < 128) {
        int h = tid >> 4, qi = tid & 15;
        size_t base = ((size_t)((n * 8 + h) * 36) + qt) * 64 + qo + qi;
        const size_t kzs = (size_t)16 * 36 * 64;
        float l = Lpart[base] + Lpart[base + kzs] + Lpart[base + 2 * kzs] + Lpart[base + 3 * kzs];
        Linv[h][qi] = 1.0f / l;
    }
    __syncthreads();
    {
        int qi = tid >> 4, dp = tid & 15, d0 = dp * 2;
        const size_t kzs = (size_t)16 * 36 * 2048;
#pragma unroll
        for (int h = 0; h < 8; ++h) {
            size_t ob = ((size_t)((n * 8 + h) * 36) + qt) * 2048 + (size_t)(qo + qi) * 32 + d0;
            float2 a = *(const float2*)&Opart[ob];
            float2 b = *(const float2*)&Opart[ob + kzs];
            float2 e = *(const float2*)&Opart[ob + 2 * kzs];
            float2 f = *(const float2*)&Opart[ob + 3 * kzs];
            float li = Linv[h][qi];
            float r0 = ((a.x + b.x) + (e.x + f.x)) * li;
            float r1 = ((a.y + b.y) + (e.y + f.y)) * li;
            *(unsigned*)&Ys[qi][h * 32 + d0] = cvt_pk_bf16(r0, r1);
        }
    }
    __syncthreads();
    int wave = tid >> 6, lane = tid & 63;
    int ln = lane & 15, quad = lane >> 4;
    int m0 = mt * 64 + wave * 16;
    const unsigned short* Abase = wob + (size_t)(m0 + ln) * 256 + quad * 8;
    f32x4 acc = (f32x4){0.f, 0.f, 0.f, 0.f};
#pragma unroll
    for (int kc = 0; kc < 8; ++kc) {
        bf16x8 a = *(const bf16x8*)(Abase + kc * 32);
        bf16x8 b = *(const bf16x8*)&Ys[ln][kc * 32 + quad * 8];
        acc = __builtin_amdgcn_mfma_f32_16x16x32_bf16(a, b, acc, 0, 0, 0);
    }
    const float c0f = 0.7f * 1.3130643285972254f;
    const float c1f = 0.3f * 1.3130643285972254f;
#pragma unroll
    for (int r = 0; r < 4; ++r) {
        int o = m0 + quad * 4 + r;
        int s = st * 16 + ln;
        size_t idx = (size_t)(n * 256 + o) * SEQ + s;
        out[idx] = c0f * x[idx] + c1f * acc[r];
    }
}

// ====================== cooperative megakernel (768 x 256, 3 blk/CU) ======================
__global__ __launch_bounds__(256, 4) void mega_kernel(
    const float* __restrict__ x,
    const float* __restrict__ w_qkv,
    const float* __restrict__ w_out,
    float* __restrict__ out,
    unsigned short* __restrict__ wqb,
    unsigned short* __restrict__ wob,
    unsigned short* __restrict__ qn,
    unsigned short* __restrict__ kn,
    unsigned short* __restrict__ vn,
    float* __restrict__ Opart,
    float* __restrict__ Lpart,
    unsigned* __restrict__ ctr)
{
    __shared__ __align__(16) unsigned char SMEM[33792];
    __shared__ int sT;
    cgx::grid_group grid = cgx::this_grid();
    int tid = threadIdx.x;
    int bid = blockIdx.x;

    // stage 0: zero counters + weight-norm (blocks 0..255)
    if (bid == 0 && tid < 3) ctr[tid] = 0;
    if (bid < 256) prep_body(bid, tid, w_qkv, w_out, wqb, wob);
    __threadfence_system();
    grid.sync();
    __threadfence_system();

    // stage 1: qkv (1152 tasks)
    for (;;) {
        __syncthreads();
        if (tid == 0) sT = atomicAdd(&ctr[0], 1);
        __syncthreads();
        int T = sT;
        if (T >= 1152) break;
        qkv_body(T, tid, SMEM, x, wqb, qn, kn, vn);
    }
    __threadfence_system();
    grid.sync();
    __threadfence_system();

    // stage 2: attention (2304 tasks)
    for (;;) {
        __syncthreads();
        if (tid == 0) sT = atomicAdd(&ctr[1], 1);
        __syncthreads();
        int T = sT;
        if (T >= 2304) break;
        attn_body(T, tid, SMEM, qn, kn, vn, Opart, Lpart);
    }
    __threadfence_system();
    grid.sync();
    __threadfence_system();

    // stage 3: reduce + out GEMM + residual (1152 tasks)
    for (;;) {
        __syncthreads();
        if (tid == 0) sT = atomicAdd(&ctr[2], 1);
        __syncthreads();
        int T = sT;
        if (T >= 1152) break;
        out_body(T, tid, SMEM, Opart, Lpart, wob, x, out);
    }
}

// ====================== fallback: proven 4-kernel pipeline (same bodies) ======================
__global__ __launch_bounds__(256) void prep_w_kernel(const float* __restrict__ w_qkv,
                                                     const float* __restrict__ w_out,
                                                     unsigned short* __restrict__ wqb,
                                                     unsigned short* __restrict__ wob) {
    prep_body(blockIdx.x, threadIdx.x, w_qkv, w_out, wqb, wob);
}
__global__ __launch_bounds__(256) void qkv_fused_kernel(const float* __restrict__ x,
                                                        const unsigned short* __restrict__ wqb,
                                                        unsigned short* __restrict__ qn,
                                                        unsigned short* __restrict__ kn,
                                                        unsigned short* __restrict__ vn) {
    __shared__ __align__(16) unsigned char SMEM[33792];
    qkv_body(blockIdx.x, threadIdx.x, SMEM, x, wqb, qn, kn, vn);
}
__global__ __launch_bounds__(256) void attn_mfma_kernel(const unsigned short* __restrict__ qn,
                                                        const unsigned short* __restrict__ kn,
                                                        const unsigned short* __restrict__ vn,
                                                        float* __restrict__ Opart,
                                                        float* __restrict__ Lpart) {
    __shared__ __align__(16) unsigned char SMEM[16384];
    attn_body(blockIdx.x, threadIdx.x, SMEM, qn, kn, vn, Opart, Lpart);
}
__global__ __launch_bounds__(256) void out_gemm_kernel(const float* __restrict__ Opart,
                                                       const float* __restrict__ Lpart,
                                                       const unsigned short* __restrict__ wob,
                                                       const float* __restrict__ x,
                                                       float* __restrict__ out) {
    __shared__ __align__(16) unsigned char SMEM[8960];
    out_body(blockIdx.x, threadIdx.x, SMEM, Opart, Lpart, wob, x, out);
}

extern "C" void kernel_launch(void* const* d_in, const int* in_sizes, int n_in,
                              void* d_out, int out_size, void* d_ws, size_t ws_size,
                              hipStream_t stream) {
    (void)in_sizes; (void)n_in; (void)out_size; (void)ws_size;
    const float* x     = (const float*)d_in[0];
    const float* w_qkv = (const float*)d_in[1];
    const float* w_out = (const float*)d_in[2];
    float* out = (float*)d_out;
    float* ws  = (float*)d_ws;
    unsigned short* wqb = (unsigned short*)(ws);             // 98304 f
    unsigned short* wob = (unsigned short*)(ws + 98304);     // 32768 f
    unsigned short* qn  = (unsigned short*)(ws + 131072);    // 589824 f each
    unsigned short* kn  = (unsigned short*)(ws + 720896);
    unsigned short* vn  = (unsigned short*)(ws + 1310720);
    float* Opart = ws + 1900544;                             // 64*36*2048 = 4718592 f
    float* Lpart = ws + 6619136;                             // 64*36*64   =  147456 f
    unsigned* ctr = (unsigned*)(ws + 6766592);               // 3 work counters

    void* ka[12];
    ka[0] = (void*)&x;     ka[1] = (void*)&w_qkv; ka[2] = (void*)&w_out;
    ka[3] = (void*)&out;   ka[4] = (void*)&wqb;   ka[5] = (void*)&wob;
    ka[6] = (void*)&qn;    ka[7] = (void*)&kn;    ka[8] = (void*)&vn;
    ka[9] = (void*)&Opart; ka[10] = (void*)&Lpart; ka[11] = (void*)&ctr;
    hipError_t err = hipLaunchCooperativeKernel((const void*)mega_kernel, dim3(768), dim3(256),
                                                ka, 0, stream);
    if (err != hipSuccess) {
        // fallback: proven 4-kernel pipeline (identical stage bodies)
        hipLaunchKernelGGL(prep_w_kernel, dim3(256), dim3(256), 0, stream,
                           w_qkv, w_out, wqb, wob);
        hipLaunchKernelGGL(qkv_fused_kernel, dim3(1152), dim3(256), 0, stream,
                           x, wqb, qn, kn, vn);
        hipLaunchKernelGGL(attn_mfma_kernel, dim3(2304), dim3(256), 0, stream,
                           qn, kn, vn, Opart, Lpart);
        hipLaunchKernelGGL(out_gemm_kernel, dim3(1152), dim3(256), 0, stream,
                           Opart, Lpart, wob, x, out);
    }
}

// Round 15
// 126.001 us; speedup vs baseline: 5.3824x; 5.3824x over previous
//
#include <hip/hip_runtime.h>
#include <math.h>

#define EPSN 1e-4f
#define SEQ 2304

using bf16x8 = __attribute__((ext_vector_type(8))) short;
using f32x4  = __attribute__((ext_vector_type(4))) float;

// HW packed f32->bf16 (RNE), gfx950.
__device__ inline unsigned cvt_pk_bf16(float lo, float hi) {
    unsigned r;
    asm("v_cvt_pk_bf16_f32 %0, %1, %2" : "=v"(r) : "v"(lo), "v"(hi));
    return r;
}
// gfx950 cross-row swaps (verified passing R3-R14).
__device__ inline void permlane32_swap(unsigned &a, unsigned &b) {
    asm("v_permlane32_swap_b32 %0, %1" : "+v"(a), "+v"(b));
}
__device__ inline void permlane16_swap(unsigned &a, unsigned &b) {
    asm("v_permlane16_swap_b32 %0, %1" : "+v"(a), "+v"(b));
}

// ================= stage bodies (R14-verified: passed inside the megakernel) ==============

// prep: weight-norm for 4 rows (one per wave). bid in [0,256).
__device__ __forceinline__ void prep_body(int bid, int tid,
                                          const float* __restrict__ w_qkv,
                                          const float* __restrict__ w_out,
                                          unsigned short* __restrict__ wqb,
                                          unsigned short* __restrict__ wob) {
    int wave = tid >> 6, lane = tid & 63;
    int row = bid * 4 + wave;
    const float* src;
    unsigned short* dst;
    if (row < 768) { src = w_qkv + (size_t)row * 256; dst = wqb + (size_t)row * 256; }
    else           { src = w_out + (size_t)(row - 768) * 256; dst = wob + (size_t)(row - 768) * 256; }
    float4 v = *(const float4*)&src[lane * 4];
    float ss = v.x * v.x + v.y * v.y + v.z * v.z + v.w * v.w;
    for (int off = 32; off > 0; off >>= 1) ss += __shfl_xor(ss, off, 64);
    float sc = 1.0f / (sqrtf(ss) + 16.0f * EPSN);
    *(uint2*)&dst[lane * 4] = make_uint2(cvt_pk_bf16(v.x * sc, v.y * sc),
                                        cvt_pk_bf16(v.z * sc, v.w * sc));
}

// qkv: fused x-transpose + QKV GEMM + d-normalize. bid in [0,1152). SMEM >= 33792 B.
__device__ __forceinline__ void qkv_body(int bid, int tid, unsigned char* SMEM,
                                         const float* __restrict__ x,
                                         const unsigned short* __restrict__ wqb,
                                         unsigned short* __restrict__ qn,
                                         unsigned short* __restrict__ kn,
                                         unsigned short* __restrict__ vn) {
    unsigned short (*Xs)[264] = (unsigned short (*)[264])SMEM;            // 16896 B
    float (*Cs)[33] = (float (*)[33])(SMEM + 16896);                      // 12672 B
    float (*Vf)[33] = (float (*)[33])(SMEM + 29568);                      // 4224 B
    int xcd = bid & 7, j = bid >> 3;
    int h = j & 7;
    int tile = xcd * 18 + (j >> 3);
    int st2 = tile % 72, n = tile / 72;
    int wave = tid >> 6, lane = tid & 63;
    int ln = lane & 15, quad = lane >> 4;
    int sgrp = wave & 1, mgrp = wave >> 1;
    int s0 = st2 * 32;
    {
        int cpair = tid >> 3, sq = tid & 7;
#pragma unroll
        for (int p = 0; p < 4; ++p) {
            int c = (p * 32 + cpair) * 2;
            const float* xb = &x[(size_t)(n * 256 + c) * SEQ + s0 + sq * 4];
            float4 a = *(const float4*)xb;
            float4 b = *(const float4*)(xb + SEQ);
            *(unsigned*)&Xs[sq * 4 + 0][c] = cvt_pk_bf16(a.x, b.x);
            *(unsigned*)&Xs[sq * 4 + 1][c] = cvt_pk_bf16(a.y, b.y);
            *(unsigned*)&Xs[sq * 4 + 2][c] = cvt_pk_bf16(a.z, b.z);
            *(unsigned*)&Xs[sq * 4 + 3][c] = cvt_pk_bf16(a.w, b.w);
        }
    }
    __syncthreads();
    const unsigned short* Abase = wqb + (size_t)(h * 96 + mgrp * 48 + ln) * 256 + quad * 8;
    f32x4 acc[3];
#pragma unroll
    for (int m = 0; m < 3; ++m) acc[m] = (f32x4){0.f, 0.f, 0.f, 0.f};
#pragma unroll
    for (int kc = 0; kc < 8; ++kc) {
        bf16x8 b = *(const bf16x8*)&Xs[sgrp * 16 + ln][kc * 32 + quad * 8];
#pragma unroll
        for (int m = 0; m < 3; ++m) {
            bf16x8 a = *(const bf16x8*)(Abase + (size_t)(m * 16) * 256 + kc * 32);
            acc[m] = __builtin_amdgcn_mfma_f32_16x16x32_bf16(a, b, acc[m], 0, 0, 0);
        }
    }
#pragma unroll
    for (int m = 0; m < 3; ++m)
#pragma unroll
        for (int r = 0; r < 4; ++r)
            Cs[mgrp * 48 + m * 16 + quad * 4 + r][sgrp * 16 + ln] = acc[m][r];
    __syncthreads();
    int nh = n * 8 + h;
    if (tid < 96) {
        int sl = tid & 31, wh = tid >> 5;
        int s = st2 * 32 + sl;
        float v[32];
        float ss = 0.f;
#pragma unroll
        for (int d = 0; d < 32; ++d) { v[d] = Cs[3 * d + wh][sl]; ss += v[d] * v[d]; }
        float inv = 1.0f / (EPSN + sqrtf(ss * (1.0f / 32.0f)));
        // fold softmax scale (1/sqrt(32)) AND log2(e) into q so attn uses exp2
        if (wh == 0) inv *= 0.17677669529663687f * 1.4426950408889634f;
        if (wh == 2) {
#pragma unroll
            for (int d = 0; d < 32; ++d) Vf[d][sl] = v[d] * inv;
        } else {
            unsigned short* dst = (wh == 1 ? kn : qn) + (size_t)nh * 73728 + (size_t)s * 32;
            unsigned wbuf[16];
#pragma unroll
            for (int j2 = 0; j2 < 16; ++j2)
                wbuf[j2] = cvt_pk_bf16(v[2 * j2] * inv, v[2 * j2 + 1] * inv);
#pragma unroll
            for (int j2 = 0; j2 < 4; ++j2) {
                uint4 t4 = make_uint4(wbuf[4 * j2], wbuf[4 * j2 + 1], wbuf[4 * j2 + 2], wbuf[4 * j2 + 3]);
                *(uint4*)(dst + j2 * 8) = t4;
            }
        }
    }
    __syncthreads();
    {
        int d = tid >> 3, sj = (tid & 7) * 4;
        float r0 = Vf[d][sj + 0], r1 = Vf[d][sj + 1];
        float r2 = Vf[d][sj + 2], r3 = Vf[d][sj + 3];
        *(uint2*)&vn[(size_t)nh * 73728 + (size_t)d * SEQ + st2 * 32 + sj] =
            make_uint2(cvt_pk_bf16(r0, r1), cvt_pk_bf16(r2, r3));
    }
}

// attn: fragment-major LDS, split-K=4, 2-deep staging. bid in [0,2304). SMEM >= 16384 B.
__device__ __forceinline__ void attn_body(int bid, int tid, unsigned char* SMEM,
                                          const unsigned short* __restrict__ qn,
                                          const unsigned short* __restrict__ kn,
                                          const unsigned short* __restrict__ vn,
                                          float* __restrict__ Opart,
                                          float* __restrict__ Lpart) {
    unsigned char (*Ksm)[4096] = (unsigned char (*)[4096])SMEM;
    unsigned char (*Vsm)[4096] = (unsigned char (*)[4096])(SMEM + 8192);
    int wq = tid >> 6, lane = tid & 63;
    int ln = lane & 15, quad = lane >> 4;
    int xcd = bid & 7, bi = bid >> 3;       // bi 0..287
    int nh = xcd * 2 + (bi >= 144);
    int bi2 = (bi >= 144) ? bi - 144 : bi;  // 0..143
    int qt = bi2 % 36, kz = bi2 / 36;       // kz 0..3
    const unsigned short* Qg = qn + (size_t)nh * 73728;
    const unsigned short* Kg = kn + (size_t)nh * 73728;
    const unsigned short* Vg = vn + (size_t)nh * 73728;

    bf16x8 qf = *(const bf16x8*)(Qg + (size_t)(qt * 64 + wq * 16 + ln) * 32 + quad * 8);
    bf16x8 ones;
#pragma unroll
    for (int i = 0; i < 8; ++i) ones[i] = (short)0x3F80;

    f32x4 o0 = {0.f, 0.f, 0.f, 0.f};
    f32x4 o1 = {0.f, 0.f, 0.f, 0.f};
    f32x4 lac = {0.f, 0.f, 0.f, 0.f};

    const int NT = 9;
    int s0 = kz * NT * 64;

    int kr = tid >> 2, kg = tid & 3;
    int koff = ((kr >> 4) << 10) | (((kg << 4) | (kr & 15)) << 4);
    int vd = tid >> 3, vg = tid & 7;
    int voff = (((vg >> 2) * 2 + (vd >> 4)) << 10) | ((((vg & 3) << 4) | (vd & 15)) << 4);
    int lb = lane << 4;

    auto compute_tile = [&](int bsel) {
        const f32x4 zero = {0.f, 0.f, 0.f, 0.f};
        unsigned w[4][2];
#pragma unroll
        for (int c = 0; c < 4; ++c) {
            bf16x8 kf = *(const bf16x8*)(Ksm[bsel] + c * 1024 + lb);
            // swapped: lane holds S[q=ln][k=c*16+quad*4+r]
            f32x4 sc = __builtin_amdgcn_mfma_f32_16x16x32_bf16(kf, qf, zero, 0, 0, 0);
            w[c][0] = cvt_pk_bf16(exp2f(sc[0]), exp2f(sc[1]));
            w[c][1] = cvt_pk_bf16(exp2f(sc[2]), exp2f(sc[3]));
        }
#pragma unroll
        for (int kc = 0; kc < 2; ++kc) {
            unsigned a0 = w[2 * kc][0], b0 = w[2 * kc + 1][0];
            permlane32_swap(a0, b0);
            permlane16_swap(a0, b0);
            unsigned a1 = w[2 * kc][1], b1 = w[2 * kc + 1][1];
            permlane32_swap(a1, b1);
            permlane16_swap(a1, b1);
            union { unsigned u[4]; bf16x8 v8; } pk;
            pk.u[0] = a0; pk.u[1] = a1; pk.u[2] = b0; pk.u[3] = b1;
            bf16x8 v0 = *(const bf16x8*)(Vsm[bsel] + (kc * 2 + 0) * 1024 + lb);
            bf16x8 v1 = *(const bf16x8*)(Vsm[bsel] + (kc * 2 + 1) * 1024 + lb);
            lac = __builtin_amdgcn_mfma_f32_16x16x32_bf16(pk.v8, ones, lac, 0, 0, 0);
            o0  = __builtin_amdgcn_mfma_f32_16x16x32_bf16(pk.v8, v0, o0, 0, 0, 0);
            o1  = __builtin_amdgcn_mfma_f32_16x16x32_bf16(pk.v8, v1, o1, 0, 0, 0);
        }
    };

    uint4 kA = *(const uint4*)(Kg + (size_t)s0 * 32 + tid * 8);
    uint4 vA = *(const uint4*)(Vg + (size_t)(tid >> 3) * SEQ + s0 + (tid & 7) * 8);
    *(uint4*)(Ksm[0] + koff) = kA;
    *(uint4*)(Vsm[0] + voff) = vA;
    uint4 kB = *(const uint4*)(Kg + (size_t)(s0 + 64) * 32 + tid * 8);
    uint4 vB = *(const uint4*)(Vg + (size_t)(tid >> 3) * SEQ + (s0 + 64) + (tid & 7) * 8);

    for (int i = 0; i < NT; i += 2) {
        if (i + 2 < NT) {
            int sn = s0 + (i + 2) * 64;
            kA = *(const uint4*)(Kg + (size_t)sn * 32 + tid * 8);
            vA = *(const uint4*)(Vg + (size_t)(tid >> 3) * SEQ + sn + (tid & 7) * 8);
        }
        __syncthreads();
        compute_tile(0);
        if (i + 1 < NT) {
            *(uint4*)(Ksm[1] + koff) = kB;
            *(uint4*)(Vsm[1] + voff) = vB;
        }
        if (i + 3 < NT) {
            int sn = s0 + (i + 3) * 64;
            kB = *(const uint4*)(Kg + (size_t)sn * 32 + tid * 8);
            vB = *(const uint4*)(Vg + (size_t)(tid >> 3) * SEQ + sn + (tid & 7) * 8);
        }
        __syncthreads();
        if (i + 1 < NT) compute_tile(1);
        if (i + 2 < NT) {
            *(uint4*)(Ksm[0] + koff) = kA;
            *(uint4*)(Vsm[0] + voff) = vA;
        }
    }

    float* Ob = Opart + ((size_t)(kz * 16 + nh) * 36 + qt) * 2048;
    float* Lb = Lpart + ((size_t)(kz * 16 + nh) * 36 + qt) * 64;
#pragma unroll
    for (int r = 0; r < 4; ++r) {
        int ql = wq * 16 + quad * 4 + r;
        Ob[ql * 32 + ln]      = o0[r];
        Ob[ql * 32 + 16 + ln] = o1[r];
        if (ln == 0) Lb[ql] = lac[r];
    }
}

// out: fused split-K reduce + out GEMM + residual. bid in [0,1152). SMEM >= 8960 B.
__device__ __forceinline__ void out_body(int bid, int tid, unsigned char* SMEM,
                                         const float* __restrict__ Opart,
                                         const float* __restrict__ Lpart,
                                         const unsigned short* __restrict__ wob,
                                         const float* __restrict__ x,
                                         float* __restrict__ out) {
    float (*Linv)[16] = (float (*)[16])SMEM;                              // 512 B
    unsigned short (*Ys)[264] = (unsigned short (*)[264])(SMEM + 512);    // 8448 B
    int xcd = bid & 7, j = bid >> 3;
    int mt = j & 3;
    int u = j >> 2;
    int n = u & 1;
    int st = xcd * 18 + (u >> 1);
    int qt = st >> 2;
    int qo = (st & 3) * 16;
    if (tid < 128) {
        int h = tid >> 4, qi = tid & 15;
        size_t base = ((size_t)((n * 8 + h) * 36) + qt) * 64 + qo + qi;
        const size_t kzs = (size_t)16 * 36 * 64;
        float l = Lpart[base] + Lpart[base + kzs] + Lpart[base + 2 * kzs] + Lpart[base + 3 * kzs];
        Linv[h][qi] = 1.0f / l;
    }
    __syncthreads();
    {
        int qi = tid >> 4, dp = tid & 15, d0 = dp * 2;
        const size_t kzs = (size_t)16 * 36 * 2048;
#pragma unroll
        for (int h = 0; h < 8; ++h) {
            size_t ob = ((size_t)((n * 8 + h) * 36) + qt) * 2048 + (size_t)(qo + qi) * 32 + d0;
            float2 a = *(const float2*)&Opart[ob];
            float2 b = *(const float2*)&Opart[ob + kzs];
            float2 e = *(const float2*)&Opart[ob + 2 * kzs];
            float2 f = *(const float2*)&Opart[ob + 3 * kzs];
            float li = Linv[h][qi];
            float r0 = ((a.x + b.x) + (e.x + f.x)) * li;
            float r1 = ((a.y + b.y) + (e.y + f.y)) * li;
            *(unsigned*)&Ys[qi][h * 32 + d0] = cvt_pk_bf16(r0, r1);
        }
    }
    __syncthreads();
    int wave = tid >> 6, lane = tid & 63;
    int ln = lane & 15, quad = lane >> 4;
    int m0 = mt * 64 + wave * 16;
    const unsigned short* Abase = wob + (size_t)(m0 + ln) * 256 + quad * 8;
    f32x4 acc = (f32x4){0.f, 0.f, 0.f, 0.f};
#pragma unroll
    for (int kc = 0; kc < 8; ++kc) {
        bf16x8 a = *(const bf16x8*)(Abase + kc * 32);
        bf16x8 b = *(const bf16x8*)&Ys[ln][kc * 32 + quad * 8];
        acc = __builtin_amdgcn_mfma_f32_16x16x32_bf16(a, b, acc, 0, 0, 0);
    }
    const float c0f = 0.7f * 1.3130643285972254f;
    const float c1f = 0.3f * 1.3130643285972254f;
#pragma unroll
    for (int r = 0; r < 4; ++r) {
        int o = m0 + quad * 4 + r;
        int s = st * 16 + ln;
        size_t idx = (size_t)(n * 256 + o) * SEQ + s;
        out[idx] = c0f * x[idx] + c1f * acc[r];
    }
}

// ====================== 4-kernel pipeline (primary; R14-verified bodies) ======================
__global__ __launch_bounds__(256) void prep_w_kernel(const float* __restrict__ w_qkv,
                                                     const float* __restrict__ w_out,
                                                     unsigned short* __restrict__ wqb,
                                                     unsigned short* __restrict__ wob) {
    prep_body(blockIdx.x, threadIdx.x, w_qkv, w_out, wqb, wob);
}
__global__ __launch_bounds__(256) void qkv_fused_kernel(const float* __restrict__ x,
                                                        const unsigned short* __restrict__ wqb,
                                                        unsigned short* __restrict__ qn,
                                                        unsigned short* __restrict__ kn,
                                                        unsigned short* __restrict__ vn) {
    __shared__ __align__(16) unsigned char SMEM[33792];
    qkv_body(blockIdx.x, threadIdx.x, SMEM, x, wqb, qn, kn, vn);
}
__global__ __launch_bounds__(256) void attn_mfma_kernel(const unsigned short* __restrict__ qn,
                                                        const unsigned short* __restrict__ kn,
                                                        const unsigned short* __restrict__ vn,
                                                        float* __restrict__ Opart,
                                                        float* __restrict__ Lpart) {
    __shared__ __align__(16) unsigned char SMEM[16384];
    attn_body(blockIdx.x, threadIdx.x, SMEM, qn, kn, vn, Opart, Lpart);
}
__global__ __launch_bounds__(256) void out_gemm_kernel(const float* __restrict__ Opart,
                                                       const float* __restrict__ Lpart,
                                                       const unsigned short* __restrict__ wob,
                                                       const float* __restrict__ x,
                                                       float* __restrict__ out) {
    __shared__ __align__(16) unsigned char SMEM[8960];
    out_body(blockIdx.x, threadIdx.x, SMEM, Opart, Lpart, wob, x, out);
}

extern "C" void kernel_launch(void* const* d_in, const int* in_sizes, int n_in,
                              void* d_out, int out_size, void* d_ws, size_t ws_size,
                              hipStream_t stream) {
    (void)in_sizes; (void)n_in; (void)out_size; (void)ws_size;
    const float* x     = (const float*)d_in[0];
    const float* w_qkv = (const float*)d_in[1];
    const float* w_out = (const float*)d_in[2];
    float* out = (float*)d_out;
    float* ws  = (float*)d_ws;
    unsigned short* wqb = (unsigned short*)(ws);             // 98304 f
    unsigned short* wob = (unsigned short*)(ws + 98304);     // 32768 f
    unsigned short* qn  = (unsigned short*)(ws + 131072);    // 589824 f each
    unsigned short* kn  = (unsigned short*)(ws + 720896);
    unsigned short* vn  = (unsigned short*)(ws + 1310720);
    float* Opart = ws + 1900544;                             // 64*36*2048 = 4718592 f
    float* Lpart = ws + 6619136;                             // 64*36*64   =  147456 f

    hipLaunchKernelGGL(prep_w_kernel, dim3(256), dim3(256), 0, stream,
                       w_qkv, w_out, wqb, wob);
    hipLaunchKernelGGL(qkv_fused_kernel, dim3(1152), dim3(256), 0, stream,
                       x, wqb, qn, kn, vn);
    hipLaunchKernelGGL(attn_mfma_kernel, dim3(2304), dim3(256), 0, stream,
                       qn, kn, vn, Opart, Lpart);
    hipLaunchKernelGGL(out_gemm_kernel, dim3(1152), dim3(256), 0, stream,
                       Opart, Lpart, wob, x, out);
}